// Round 1
// baseline (803.080 us; speedup 1.0000x reference)
//
#include <hip/hip_runtime.h>

// y = (x + 2) + (x * 3) - (x - 1) * (x * 0.5), elementwise fp32.
// Memory-bound: 1.07 GB total traffic -> ~170 us at 6.3 TB/s achievable.

__device__ __forceinline__ float fuse1(float x) {
    // Keep the reference's operation order for bit-compatible rounding.
    return (x + 2.0f) + (x * 3.0f) - (x - 1.0f) * (x * 0.5f);
}

__global__ __launch_bounds__(256) void fused_elemwise_kernel(
    const float* __restrict__ x, float* __restrict__ out, long long n4) {
    long long i = (long long)blockIdx.x * blockDim.x + threadIdx.x;
    if (i >= n4) return;
    const float4* __restrict__ x4 = (const float4*)x;
    float4* __restrict__ o4 = (float4*)out;
    float4 v = x4[i];
    float4 r;
    r.x = fuse1(v.x);
    r.y = fuse1(v.y);
    r.z = fuse1(v.z);
    r.w = fuse1(v.w);
    o4[i] = r;
}

extern "C" void kernel_launch(void* const* d_in, const int* in_sizes, int n_in,
                              void* d_out, int out_size, void* d_ws, size_t ws_size,
                              hipStream_t stream) {
    const float* x = (const float*)d_in[0];
    float* out = (float*)d_out;
    long long n = (long long)in_sizes[0];      // 134217728, divisible by 4
    long long n4 = n / 4;                       // 33554432
    int block = 256;
    long long grid = (n4 + block - 1) / block;  // 131072 blocks
    fused_elemwise_kernel<<<(dim3)(unsigned)grid, block, 0, stream>>>(x, out, n4);
}